// Round 1
// baseline (724.701 us; speedup 1.0000x reference)
//
#include <hip/hip_runtime.h>

typedef __attribute__((ext_vector_type(8))) short short8;
typedef __attribute__((ext_vector_type(4))) short short4v;
typedef __attribute__((ext_vector_type(4))) float f32x4;

#define B_  4
#define T_  2048
#define D_  1024
#define H_  16
#define HD_ 64

__device__ __forceinline__ short f2bf(float f) {
  unsigned u = __builtin_bit_cast(unsigned, f);
  u = (u + 0x7FFFu + ((u >> 16) & 1u)) >> 16;
  return (short)u;
}

// async global->LDS, 16B per lane. lds ptr must be wave-uniform; HW adds lane*16.
__device__ __forceinline__ void g2l16(const void* g, void* l) {
  __builtin_amdgcn_global_load_lds((const __attribute__((address_space(1))) void*)g,
                                   (__attribute__((address_space(3))) void*)l, 16, 0, 0);
}

// ---------------- elementwise cast fp32 -> bf16 ----------------
__global__ __launch_bounds__(256) void cast_x_kernel(const float* __restrict__ src,
                                                     short* __restrict__ dst) {
  int i = (blockIdx.x * 256 + threadIdx.x) * 4;
  float4 v = *(const float4*)(src + i);
  short4v o;
  o.x = f2bf(v.x); o.y = f2bf(v.y); o.z = f2bf(v.z); o.w = f2bf(v.w);
  *(short4v*)(dst + i) = o;
}

// ---------------- transpose-cast fp32 [R][C] -> bf16 [C][R] ----------------
__global__ __launch_bounds__(256) void tcast_kernel(const float* __restrict__ src,
                                                    short* __restrict__ dst, int R, int C) {
  __shared__ float tile[32][33];
  int cb = blockIdx.x, rb = blockIdx.y;
  int tr = threadIdx.x >> 5, tc = threadIdx.x & 31;
#pragma unroll
  for (int p = 0; p < 4; ++p) {
    int r = p * 8 + tr;
    tile[r][tc] = src[(size_t)(rb * 32 + r) * C + cb * 32 + tc];
  }
  __syncthreads();
#pragma unroll
  for (int p = 0; p < 4; ++p) {
    int r = p * 8 + tr;
    dst[(size_t)(cb * 32 + r) * R + rb * 32 + tc] = f2bf(tile[tc][r]);
  }
}

// ---------------- batched bf16 transpose [BH][T][64] -> [BH][64][T] ----------------
__global__ __launch_bounds__(256) void btransV_kernel(const short* __restrict__ src,
                                                      short* __restrict__ dst) {
  __shared__ short tile[32][33];
  int tb = blockIdx.x, hb = blockIdx.y, bh = blockIdx.z;
  int tr = threadIdx.x >> 5, tc = threadIdx.x & 31;
  const short* s = src + (size_t)bh * (T_ * HD_);
  short* d = dst + (size_t)bh * (T_ * HD_);
#pragma unroll
  for (int p = 0; p < 4; ++p) {
    int r = p * 8 + tr;
    tile[r][tc] = s[(tb * 32 + r) * HD_ + hb * 32 + tc];
  }
  __syncthreads();
#pragma unroll
  for (int p = 0; p < 4; ++p) {
    int r = p * 8 + tr;
    d[(size_t)(hb * 32 + r) * T_ + tb * 32 + tc] = tile[tc][r];
  }
}

// ---------------- GEMM core: C[128x128] = A[M,K] @ Bt[N,K]^T tile ----------------
// m97 structure: chunk-major LDS (slot16(kc,r) = kc*128+r), global_load_lds width 16.
__device__ __forceinline__ void gemm_core(const short* __restrict__ A, const short* __restrict__ Bt,
                                          int K, int mb, int nb, short* As, short* Bs,
                                          f32x4 acc[4][4]) {
  const int tid = threadIdx.x;
  const int wave = tid >> 6, lane = tid & 63;
  const int quad = lane >> 4, l15 = lane & 15;
  const int wr = wave >> 1, wc = wave & 1;
  f32x4 zero = {0.f, 0.f, 0.f, 0.f};
#pragma unroll
  for (int i = 0; i < 4; ++i)
#pragma unroll
    for (int j = 0; j < 4; ++j) acc[i][j] = zero;

  const int nK = K >> 5;
  for (int kk = 0; kk < nK; ++kk) {
    __syncthreads();  // WAR: previous iter's frag reads complete
#pragma unroll
    for (int i = 0; i < 2; ++i) {
      int sbase = i * 256 + wave * 64;   // wave-uniform
      int s = sbase + lane;
      int kc = s >> 7, r = s & 127;
      g2l16(A + (size_t)(mb * 128 + r) * K + kk * 32 + kc * 8, As + sbase * 8);
      g2l16(Bt + (size_t)(nb * 128 + r) * K + kk * 32 + kc * 8, Bs + sbase * 8);
    }
    __syncthreads();  // drains vmcnt -> staging visible

    short8 af[4], bq[4];
#pragma unroll
    for (int t = 0; t < 4; ++t) {
      af[t] = *(const short8*)(As + (quad * 128 + wr * 64 + t * 16 + l15) * 8);
      bq[t] = *(const short8*)(Bs + (quad * 128 + wc * 64 + t * 16 + l15) * 8);
    }
#pragma unroll
    for (int i = 0; i < 4; ++i)
#pragma unroll
      for (int j = 0; j < 4; ++j)
        acc[i][j] = __builtin_amdgcn_mfma_f32_16x16x32_bf16(af[i], bq[j], acc[i][j], 0, 0, 0);
  }
}

// ---------------- GEMM1: qkv = x @ Wqkv + bqkv, scatter to Q/K/V layouts ----------------
__global__ __launch_bounds__(256, 2) void gemm_qkv_kernel(
    const short* __restrict__ xb, const short* __restrict__ Wqt, const float* __restrict__ bqkv,
    short* __restrict__ Qb, short* __restrict__ Kb, short* __restrict__ Vb) {
  __shared__ alignas(16) short As[4096];
  __shared__ alignas(16) short Bs[4096];
  f32x4 acc[4][4];
  int nb = blockIdx.x, mb = blockIdx.y;
  gemm_core(xb, Wqt, D_, mb, nb, As, Bs, acc);

  const int tid = threadIdx.x, wave = tid >> 6, lane = tid & 63;
  const int quad = lane >> 4, l15 = lane & 15;
  const int wr = wave >> 1, wc = wave & 1;
  int part = nb >> 3;  // 0=Q, 1=K, 2=V (uniform per block)
  short* dst = (part == 0) ? Qb : ((part == 1) ? Kb : Vb);
  int h = ((nb & 7) << 1) + wc;  // head (uniform per wave)
#pragma unroll
  for (int j = 0; j < 4; ++j) {
    int n = nb * 128 + wc * 64 + j * 16 + l15;
    int hd = j * 16 + l15;
    float bv = bqkv[n];
#pragma unroll
    for (int i = 0; i < 4; ++i) {
      int mrow = mb * 128 + wr * 64 + i * 16 + quad * 4;
#pragma unroll
      for (int rr = 0; rr < 4; ++rr) {
        int m = mrow + rr;
        int b = m >> 11, t = m & 2047;
        dst[((size_t)((b * H_ + h) * T_ + t)) * HD_ + hd] = f2bf(acc[i][j][rr] + bv);
      }
    }
  }
}

// ---------------- GEMM2: out = attn_out @ Wout + bout (fp32 out) ----------------
__global__ __launch_bounds__(256, 2) void gemm_out_kernel(
    const short* __restrict__ Ob, const short* __restrict__ Wot,
    const float* __restrict__ bout, float* __restrict__ out) {
  __shared__ alignas(16) short As[4096];
  __shared__ alignas(16) short Bs[4096];
  f32x4 acc[4][4];
  int nb = blockIdx.x, mb = blockIdx.y;
  gemm_core(Ob, Wot, D_, mb, nb, As, Bs, acc);

  const int tid = threadIdx.x, wave = tid >> 6, lane = tid & 63;
  const int quad = lane >> 4, l15 = lane & 15;
  const int wr = wave >> 1, wc = wave & 1;
#pragma unroll
  for (int j = 0; j < 4; ++j) {
    int n = nb * 128 + wc * 64 + j * 16 + l15;
    float bv = bout[n];
#pragma unroll
    for (int i = 0; i < 4; ++i) {
      int mrow = mb * 128 + wr * 64 + i * 16 + quad * 4;
#pragma unroll
      for (int rr = 0; rr < 4; ++rr) {
        out[(size_t)(mrow + rr) * D_ + n] = acc[i][j][rr] + bv;
      }
    }
  }
}

// ---------------- Flash attention with entity bias + causal mask ----------------
// block = (bh, qtile of 128). 4 waves x 32 queries. K-tiles of 128, kt <= qt.
__global__ __launch_bounds__(256, 2) void attn_kernel(
    const short* __restrict__ Qb, const short* __restrict__ Kb, const short* __restrict__ Vt,
    const float* __restrict__ bias, short* __restrict__ Ob) {
  __shared__ alignas(16) short Qs[8192];  // slot16(kc0..7, r0..127) = kc*128+r ; (query r, hd kc*8+j)
  __shared__ alignas(16) short Ks[8192];  // same, r = key
  __shared__ alignas(16) short Vs[8192];  // slot16(kc0..15, r0..63) = kc*64+r ; (hd r, key kc*8+j)
  __shared__ alignas(16) short Ps[4][1024];  // per-wave P chunk: slot16 = (keyc>>3)*32 + q

  const int tid = threadIdx.x, wave = tid >> 6, lane = tid & 63;
  const int quad = lane >> 4, l15 = lane & 15;
  const int bh = blockIdx.x;
  const int qt = 15 - (int)blockIdx.y;  // heavy blocks first
  const int b = bh >> 4;

  // stage Q (async; drained by first in-loop barrier)
#pragma unroll
  for (int i = 0; i < 4; ++i) {
    int sbase = i * 256 + wave * 64;
    int s = sbase + lane;
    int kc = s >> 7, r = s & 127;
    g2l16(Qb + ((size_t)bh * T_ + qt * 128 + r) * HD_ + kc * 8, Qs + sbase * 8);
  }

  f32x4 zero = {0.f, 0.f, 0.f, 0.f};
  f32x4 o[2][4];
  float mi[2][4], li[2][4];
#pragma unroll
  for (int ti = 0; ti < 2; ++ti) {
#pragma unroll
    for (int hj = 0; hj < 4; ++hj) o[ti][hj] = zero;
#pragma unroll
    for (int rr = 0; rr < 4; ++rr) { mi[ti][rr] = -3.0e38f; li[ti][rr] = 0.f; }
  }

  const float scale = 0.125f;               // 1/sqrt(64)
  const float LOG2E = 1.4426950408889634f;

  for (int kt = 0; kt <= qt; ++kt) {
    __syncthreads();  // WAR: previous iteration's K/V frag reads done
#pragma unroll
    for (int i = 0; i < 4; ++i) {
      int sbase = i * 256 + wave * 64;
      int s = sbase + lane;
      int kc = s >> 7, r = s & 127;
      g2l16(Kb + ((size_t)bh * T_ + kt * 128 + r) * HD_ + kc * 8, Ks + sbase * 8);
      int kc2 = s >> 6, r2 = s & 63;
      g2l16(Vt + ((size_t)bh * HD_ + r2) * T_ + kt * 128 + kc2 * 8, Vs + sbase * 8);
    }
    __syncthreads();  // staging (incl. Q on first iter) visible

    // ---- S = (Q K^T) * scale + bias, causal mask ----
    short8 aq[2][2];
#pragma unroll
    for (int ti = 0; ti < 2; ++ti)
#pragma unroll
      for (int c2 = 0; c2 < 2; ++c2)
        aq[ti][c2] = *(const short8*)(Qs + ((c2 * 4 + quad) * 128 + wave * 32 + ti * 16 + l15) * 8);

    f32x4 sc[2][8];
#pragma unroll
    for (int tj = 0; tj < 8; ++tj) {
      short8 bk0 = *(const short8*)(Ks + ((0 * 4 + quad) * 128 + tj * 16 + l15) * 8);
      short8 bk1 = *(const short8*)(Ks + ((1 * 4 + quad) * 128 + tj * 16 + l15) * 8);
#pragma unroll
      for (int ti = 0; ti < 2; ++ti) {
        f32x4 a = zero;
        a = __builtin_amdgcn_mfma_f32_16x16x32_bf16(aq[ti][0], bk0, a, 0, 0, 0);
        a = __builtin_amdgcn_mfma_f32_16x16x32_bf16(aq[ti][1], bk1, a, 0, 0, 0);
        sc[ti][tj] = a;
      }
    }
    bool diag = (kt == qt);
#pragma unroll
    for (int ti = 0; ti < 2; ++ti) {
#pragma unroll
      for (int tj = 0; tj < 8; ++tj) {
        int kl = tj * 16 + l15;
        int kg = kt * 128 + kl;
#pragma unroll
        for (int rr = 0; rr < 4; ++rr) {
          int ql = wave * 32 + ti * 16 + quad * 4 + rr;
          int qg = qt * 128 + ql;
          float x = sc[ti][tj][rr] * scale + bias[((size_t)b * T_ + qg) * T_ + kg];
          if (diag && kl > ql) x = -1.0e30f;
          sc[ti][tj][rr] = x;
        }
      }
    }

    // ---- online softmax (row reductions across quad lanes) ----
#pragma unroll
    for (int ti = 0; ti < 2; ++ti) {
      float rmax[4];
#pragma unroll
      for (int rr = 0; rr < 4; ++rr) {
        float m = sc[ti][0][rr];
#pragma unroll
        for (int tj = 1; tj < 8; ++tj) m = fmaxf(m, sc[ti][tj][rr]);
        rmax[rr] = m;
      }
#pragma unroll
      for (int d = 1; d < 16; d <<= 1)
#pragma unroll
        for (int rr = 0; rr < 4; ++rr) rmax[rr] = fmaxf(rmax[rr], __shfl_xor(rmax[rr], d, 64));
      float alpha[4];
#pragma unroll
      for (int rr = 0; rr < 4; ++rr) {
        float mnew = fmaxf(mi[ti][rr], rmax[rr]);
        alpha[rr] = exp2f((mi[ti][rr] - mnew) * LOG2E);
        mi[ti][rr] = mnew;
      }
      float rsum[4] = {0.f, 0.f, 0.f, 0.f};
#pragma unroll
      for (int tj = 0; tj < 8; ++tj)
#pragma unroll
        for (int rr = 0; rr < 4; ++rr) {
          float p = exp2f((sc[ti][tj][rr] - mi[ti][rr]) * LOG2E);
          sc[ti][tj][rr] = p;
          rsum[rr] += p;
        }
#pragma unroll
      for (int d = 1; d < 16; d <<= 1)
#pragma unroll
        for (int rr = 0; rr < 4; ++rr) rsum[rr] += __shfl_xor(rsum[rr], d, 64);
#pragma unroll
      for (int rr = 0; rr < 4; ++rr) li[ti][rr] = li[ti][rr] * alpha[rr] + rsum[rr];
#pragma unroll
      for (int hj = 0; hj < 4; ++hj)
#pragma unroll
        for (int rr = 0; rr < 4; ++rr) o[ti][hj][rr] *= alpha[rr];
    }

    // ---- O += P @ V  (P transposed C-layout -> A-layout via per-wave LDS) ----
    short* pw = &Ps[wave][0];
#pragma unroll
    for (int kc = 0; kc < 4; ++kc) {
#pragma unroll
      for (int ti = 0; ti < 2; ++ti)
#pragma unroll
        for (int tp = 0; tp < 2; ++tp) {
          int tj = kc * 2 + tp;
          int klc = tp * 16 + l15;  // key within 32-chunk
#pragma unroll
          for (int rr = 0; rr < 4; ++rr) {
            int q = ti * 16 + quad * 4 + rr;
            pw[((klc >> 3) * 32 + q) * 8 + (klc & 7)] = f2bf(sc[ti][tj][rr]);
          }
        }
#pragma unroll
      for (int ti = 0; ti < 2; ++ti) {
        short8 ap = *(const short8*)(pw + (quad * 32 + ti * 16 + l15) * 8);
#pragma unroll
        for (int hj = 0; hj < 4; ++hj) {
          short8 bv = *(const short8*)(Vs + ((kc * 4 + quad) * 64 + hj * 16 + l15) * 8);
          o[ti][hj] = __builtin_amdgcn_mfma_f32_16x16x32_bf16(ap, bv, o[ti][hj], 0, 0, 0);
        }
      }
    }
  }

  // ---- epilogue: O / l -> Obuf[B,T,D] bf16 ----
  int h = bh & 15;
#pragma unroll
  for (int ti = 0; ti < 2; ++ti)
#pragma unroll
    for (int hj = 0; hj < 4; ++hj)
#pragma unroll
      for (int rr = 0; rr < 4; ++rr) {
        int q = qt * 128 + wave * 32 + ti * 16 + quad * 4 + rr;
        int dcol = h * 64 + hj * 16 + l15;
        Ob[((size_t)b * T_ + q) * D_ + dcol] = f2bf(o[ti][hj][rr] / li[ti][rr]);
      }
}

// ---------------- host launcher ----------------
extern "C" void kernel_launch(void* const* d_in, const int* in_sizes, int n_in,
                              void* d_out, int out_size, void* d_ws, size_t ws_size,
                              hipStream_t stream) {
  const float* x    = (const float*)d_in[0];
  const float* bias = (const float*)d_in[1];
  const float* Wqkv = (const float*)d_in[2];
  const float* bqkv = (const float*)d_in[3];
  const float* Wout = (const float*)d_in[4];
  const float* bout = (const float*)d_in[5];
  float* out = (float*)d_out;
  char* ws = (char*)d_ws;

  // workspace layout (75.5 MB total, with lifetime-based aliasing)
  short* xb   = (short*)(ws + 0);          // x bf16 [8192][1024]      (dead after gemm1)
  short* Vt   = (short*)(ws + 0);          // V^T [BH][64][T]          (aliases xb)
  short* Wqt  = (short*)(ws + 16777216);   // Wqkv^T bf16 [3072][1024]
  short* Wot  = (short*)(ws + 23068672);   // Wout^T bf16 [1024][1024]
  short* Qb   = (short*)(ws + 25165824);   // Q [BH][T][64]
  short* Kb   = (short*)(ws + 41943040);   // K [BH][T][64]
  short* Vtmp = (short*)(ws + 58720256);   // V [BH][T][64]            (dead after btransV)
  short* Ob   = (short*)(ws + 58720256);   // attn out [B,T,D] bf16    (aliases Vtmp)

  cast_x_kernel<<<8192, 256, 0, stream>>>(x, xb);
  tcast_kernel<<<dim3(96, 32), 256, 0, stream>>>(Wqkv, Wqt, 1024, 3072);
  tcast_kernel<<<dim3(32, 32), 256, 0, stream>>>(Wout, Wot, 1024, 1024);
  gemm_qkv_kernel<<<dim3(24, 64), 256, 0, stream>>>(xb, Wqt, bqkv, Qb, Kb, Vtmp);
  btransV_kernel<<<dim3(64, 2, 64), 256, 0, stream>>>(Vtmp, Vt);
  attn_kernel<<<dim3(64, 16), 256, 0, stream>>>(Qb, Kb, Vt, bias, Ob);
  gemm_out_kernel<<<dim3(8, 64), 256, 0, stream>>>(Ob, Wot, bout, out);
}

// Round 2
// 442.304 us; speedup vs baseline: 1.6385x; 1.6385x over previous
//
#include <hip/hip_runtime.h>

typedef __attribute__((ext_vector_type(8))) short short8;
typedef __attribute__((ext_vector_type(4))) short short4v;
typedef __attribute__((ext_vector_type(4))) float f32x4;

#define B_  4
#define T_  2048
#define D_  1024
#define H_  16
#define HD_ 64

#define LOG2E 1.4426950408889634f
#define QSCALE 0.1803368801111243f   /* 0.125 * log2(e) */

__device__ __forceinline__ short f2bf(float f) {
  unsigned u = __builtin_bit_cast(unsigned, f);
  u = (u + 0x7FFFu + ((u >> 16) & 1u)) >> 16;
  return (short)u;
}
__device__ __forceinline__ float bf2f(short s) {
  unsigned u = ((unsigned)(unsigned short)s) << 16;
  return __builtin_bit_cast(float, u);
}

// async global->LDS, 16B per lane. lds ptr must be wave-uniform; HW adds lane*16.
__device__ __forceinline__ void g2l16(const void* g, void* l) {
  __builtin_amdgcn_global_load_lds((const __attribute__((address_space(1))) void*)g,
                                   (__attribute__((address_space(3))) void*)l, 16, 0, 0);
}

// ---------------- elementwise cast fp32 -> bf16 ----------------
__global__ __launch_bounds__(256) void cast_x_kernel(const float* __restrict__ src,
                                                     short* __restrict__ dst) {
  int i = (blockIdx.x * 256 + threadIdx.x) * 4;
  float4 v = *(const float4*)(src + i);
  short4v o;
  o.x = f2bf(v.x); o.y = f2bf(v.y); o.z = f2bf(v.z); o.w = f2bf(v.w);
  *(short4v*)(dst + i) = o;
}

// ---------------- transpose-cast fp32 [R][C] -> bf16 [C][R] ----------------
__global__ __launch_bounds__(256) void tcast_kernel(const float* __restrict__ src,
                                                    short* __restrict__ dst, int R, int C) {
  __shared__ float tile[32][33];
  int cb = blockIdx.x, rb = blockIdx.y;
  int tr = threadIdx.x >> 5, tc = threadIdx.x & 31;
#pragma unroll
  for (int p = 0; p < 4; ++p) {
    int r = p * 8 + tr;
    tile[r][tc] = src[(size_t)(rb * 32 + r) * C + cb * 32 + tc];
  }
  __syncthreads();
#pragma unroll
  for (int p = 0; p < 4; ++p) {
    int r = p * 8 + tr;
    dst[(size_t)(cb * 32 + r) * R + rb * 32 + tc] = f2bf(tile[tc][r]);
  }
}

// ---------------- batched bf16 transpose [BH][T][64] -> [BH][64][T] ----------------
__global__ __launch_bounds__(256) void btransV_kernel(const short* __restrict__ src,
                                                      short* __restrict__ dst) {
  __shared__ short tile[32][33];
  int tb = blockIdx.x, hb = blockIdx.y, bh = blockIdx.z;
  int tr = threadIdx.x >> 5, tc = threadIdx.x & 31;
  const short* s = src + (size_t)bh * (T_ * HD_);
  short* d = dst + (size_t)bh * (T_ * HD_);
#pragma unroll
  for (int p = 0; p < 4; ++p) {
    int r = p * 8 + tr;
    tile[r][tc] = s[(tb * 32 + r) * HD_ + hb * 32 + tc];
  }
  __syncthreads();
#pragma unroll
  for (int p = 0; p < 4; ++p) {
    int r = p * 8 + tr;
    d[(size_t)(hb * 32 + r) * T_ + tb * 32 + tc] = tile[tc][r];
  }
}

// ---------------- bias -> C-fragment-layout bf16 tiles (mask + log2e folded) ----------
// PB[(b*136 + qt*(qt+1)/2 + kt)][tid 0..511][tj 0..7][rr 0..3]  (bf16)
__global__ __launch_bounds__(512) void pb_kernel(const float* __restrict__ bias,
                                                 short* __restrict__ PB) {
  int bid = blockIdx.x;            // 0..543
  int b = bid / 136, tidx = bid % 136;
  int qt = 0, base = 0;
  while (base + qt + 1 <= tidx) { base += qt + 1; ++qt; }
  int kt = tidx - base;
  int tid = threadIdx.x;
  int w = tid >> 6, lane = tid & 63, quad = lane >> 4, l15 = lane & 15;
  short vals[32];
#pragma unroll
  for (int tj = 0; tj < 8; ++tj)
#pragma unroll
    for (int rr = 0; rr < 4; ++rr) {
      int ql = w * 16 + quad * 4 + rr;
      int kl = tj * 16 + l15;
      float v = bias[((size_t)b * T_ + qt * 128 + ql) * T_ + kt * 128 + kl] * LOG2E;
      if (kt == qt && kl > ql) v = -1.0e9f;
      vals[tj * 4 + rr] = f2bf(v);
    }
  short* dst = PB + ((size_t)bid * 512 + tid) * 32;
#pragma unroll
  for (int j = 0; j < 4; ++j) *(short8*)(dst + j * 8) = *(const short8*)(vals + j * 8);
}

// ---------------- GEMM core: C[128x128] = A[M,K] @ Bt[N,K]^T tile ----------------
__device__ __forceinline__ void gemm_core(const short* __restrict__ A, const short* __restrict__ Bt,
                                          int K, int mb, int nb, short* As, short* Bs,
                                          f32x4 acc[4][4]) {
  const int tid = threadIdx.x;
  const int wave = tid >> 6, lane = tid & 63;
  const int quad = lane >> 4, l15 = lane & 15;
  const int wr = wave >> 1, wc = wave & 1;
  f32x4 zero = {0.f, 0.f, 0.f, 0.f};
#pragma unroll
  for (int i = 0; i < 4; ++i)
#pragma unroll
    for (int j = 0; j < 4; ++j) acc[i][j] = zero;

  const int nK = K >> 5;
  for (int kk = 0; kk < nK; ++kk) {
    __syncthreads();
#pragma unroll
    for (int i = 0; i < 2; ++i) {
      int sbase = i * 256 + wave * 64;
      int s = sbase + lane;
      int kc = s >> 7, r = s & 127;
      g2l16(A + (size_t)(mb * 128 + r) * K + kk * 32 + kc * 8, As + sbase * 8);
      g2l16(Bt + (size_t)(nb * 128 + r) * K + kk * 32 + kc * 8, Bs + sbase * 8);
    }
    __syncthreads();

    short8 af[4], bq[4];
#pragma unroll
    for (int t = 0; t < 4; ++t) {
      af[t] = *(const short8*)(As + (quad * 128 + wr * 64 + t * 16 + l15) * 8);
      bq[t] = *(const short8*)(Bs + (quad * 128 + wc * 64 + t * 16 + l15) * 8);
    }
#pragma unroll
    for (int i = 0; i < 4; ++i)
#pragma unroll
      for (int j = 0; j < 4; ++j)
        acc[i][j] = __builtin_amdgcn_mfma_f32_16x16x32_bf16(af[i], bq[j], acc[i][j], 0, 0, 0);
  }
}

// ---------------- GEMM1: qkv = x @ Wqkv + bqkv, scatter; Q pre-scaled -----------
__global__ __launch_bounds__(256, 2) void gemm_qkv_kernel(
    const short* __restrict__ xb, const short* __restrict__ Wqt, const float* __restrict__ bqkv,
    short* __restrict__ Qb, short* __restrict__ Kb, short* __restrict__ Vb) {
  __shared__ alignas(16) short As[4096];
  __shared__ alignas(16) short Bs[4096];
  f32x4 acc[4][4];
  int nb = blockIdx.x, mb = blockIdx.y;
  gemm_core(xb, Wqt, D_, mb, nb, As, Bs, acc);

  const int tid = threadIdx.x, wave = tid >> 6, lane = tid & 63;
  const int quad = lane >> 4, l15 = lane & 15;
  const int wr = wave >> 1, wc = wave & 1;
  int part = nb >> 3;
  short* dst = (part == 0) ? Qb : ((part == 1) ? Kb : Vb);
  float sc = (part == 0) ? QSCALE : 1.0f;   // fold attn scale*log2e into Q
  int h = ((nb & 7) << 1) + wc;
#pragma unroll
  for (int j = 0; j < 4; ++j) {
    int n = nb * 128 + wc * 64 + j * 16 + l15;
    int hd = j * 16 + l15;
    float bv = bqkv[n];
#pragma unroll
    for (int i = 0; i < 4; ++i) {
      int mrow = mb * 128 + wr * 64 + i * 16 + quad * 4;
#pragma unroll
      for (int rr = 0; rr < 4; ++rr) {
        int m = mrow + rr;
        int b = m >> 11, t = m & 2047;
        dst[((size_t)((b * H_ + h) * T_ + t)) * HD_ + hd] = f2bf((acc[i][j][rr] + bv) * sc);
      }
    }
  }
}

// ---------------- GEMM2: out = attn_out @ Wout + bout (fp32 out) ----------------
__global__ __launch_bounds__(256, 2) void gemm_out_kernel(
    const short* __restrict__ Ob, const short* __restrict__ Wot,
    const float* __restrict__ bout, float* __restrict__ out) {
  __shared__ alignas(16) short As[4096];
  __shared__ alignas(16) short Bs[4096];
  f32x4 acc[4][4];
  int nb = blockIdx.x, mb = blockIdx.y;
  gemm_core(Ob, Wot, D_, mb, nb, As, Bs, acc);

  const int tid = threadIdx.x, wave = tid >> 6, lane = tid & 63;
  const int quad = lane >> 4, l15 = lane & 15;
  const int wr = wave >> 1, wc = wave & 1;
#pragma unroll
  for (int j = 0; j < 4; ++j) {
    int n = nb * 128 + wc * 64 + j * 16 + l15;
    float bv = bout[n];
#pragma unroll
    for (int i = 0; i < 4; ++i) {
      int mrow = mb * 128 + wr * 64 + i * 16 + quad * 4;
#pragma unroll
      for (int rr = 0; rr < 4; ++rr) {
        out[(size_t)(mrow + rr) * D_ + n] = acc[i][j][rr] + bv;
      }
    }
  }
}

// ---------------- Flash attention, 512 threads (8 waves x 16 q-rows) -------------
// bias pre-baked into PB (C-fragment layout, log2e+causal folded); Q pre-scaled.
__global__ __launch_bounds__(512, 4) void attn_kernel(
    const short* __restrict__ Qb, const short* __restrict__ Kb, const short* __restrict__ Vt,
    const short* __restrict__ PB, short* __restrict__ Ob) {
  __shared__ alignas(16) short Ks[8192];     // slot16(kc0..7, key0..127) = kc*128+key
  __shared__ alignas(16) short Vs[8192];     // slot16(kc0..15, hd0..63)  = kc*64+hd
  __shared__ alignas(16) short Ps[8][512];   // per-wave P chunk 16q x 32k

  const int tid = threadIdx.x, wave = tid >> 6, lane = tid & 63;
  const int quad = lane >> 4, l15 = lane & 15;
  const int bh = blockIdx.x;
  const int qt = 15 - (int)blockIdx.y;       // heavy blocks first
  const int b = bh >> 4, h = bh & 15;

  // ---- stage Q (through Ks), pull fragments to registers ----
#pragma unroll
  for (int i = 0; i < 2; ++i) {
    int sbase = i * 512 + wave * 64;
    int s = sbase + lane;
    g2l16(Qb + ((size_t)bh * T_ + qt * 128 + (s & 127)) * HD_ + (s >> 7) * 8, Ks + sbase * 8);
  }
  __syncthreads();
  short8 aq[2];
#pragma unroll
  for (int c2 = 0; c2 < 2; ++c2)
    aq[c2] = *(const short8*)(Ks + ((c2 * 4 + quad) * 128 + wave * 16 + l15) * 8);

  f32x4 zero = {0.f, 0.f, 0.f, 0.f};
  f32x4 o[4];
  float mi[4], li[4];
#pragma unroll
  for (int hj = 0; hj < 4; ++hj) o[hj] = zero;
#pragma unroll
  for (int rr = 0; rr < 4; ++rr) { mi[rr] = -3.0e38f; li[rr] = 0.f; }

  const short* pbbase = PB + ((size_t)(b * 136 + ((qt * (qt + 1)) >> 1)) * 512 + tid) * 32;

  for (int kt = 0; kt <= qt; ++kt) {
    __syncthreads();  // WAR: previous iter's frag reads (and aq reads on iter 0) done
#pragma unroll
    for (int i = 0; i < 2; ++i) {
      int sbase = i * 512 + wave * 64;
      int s = sbase + lane;
      g2l16(Kb + ((size_t)bh * T_ + kt * 128 + (s & 127)) * HD_ + (s >> 7) * 8, Ks + sbase * 8);
      g2l16(Vt + ((size_t)bh * HD_ + (s & 63)) * T_ + kt * 128 + (s >> 6) * 8, Vs + sbase * 8);
    }
    // bias fragment prefetch (coalesced, 64B/lane); drained by the barrier below
    short8 pb[4];
    const short* pp = pbbase + (size_t)kt * (512 * 32);
#pragma unroll
    for (int j = 0; j < 4; ++j) pb[j] = *(const short8*)(pp + j * 8);
    __syncthreads();

    // ---- S(log2 domain) = sQ K^T + PB  (bias as accumulator init) ----
    f32x4 sc[8];
#pragma unroll
    for (int j4 = 0; j4 < 4; ++j4)
#pragma unroll
      for (int tp = 0; tp < 2; ++tp) {
#pragma unroll
        for (int rr = 0; rr < 4; ++rr) sc[j4 * 2 + tp][rr] = bf2f(pb[j4][tp * 4 + rr]);
      }
#pragma unroll
    for (int tj = 0; tj < 8; ++tj) {
      short8 bk0 = *(const short8*)(Ks + (quad * 128 + tj * 16 + l15) * 8);
      short8 bk1 = *(const short8*)(Ks + ((4 + quad) * 128 + tj * 16 + l15) * 8);
      sc[tj] = __builtin_amdgcn_mfma_f32_16x16x32_bf16(aq[0], bk0, sc[tj], 0, 0, 0);
      sc[tj] = __builtin_amdgcn_mfma_f32_16x16x32_bf16(aq[1], bk1, sc[tj], 0, 0, 0);
    }

    // ---- online softmax (base-2 domain; row = quad*4+rr, cols across l15) ----
    float rmax[4];
#pragma unroll
    for (int rr = 0; rr < 4; ++rr) {
      float m = sc[0][rr];
#pragma unroll
      for (int tj = 1; tj < 8; ++tj) m = fmaxf(m, sc[tj][rr]);
      rmax[rr] = m;
    }
#pragma unroll
    for (int d = 1; d < 16; d <<= 1)
#pragma unroll
      for (int rr = 0; rr < 4; ++rr) rmax[rr] = fmaxf(rmax[rr], __shfl_xor(rmax[rr], d, 64));
    float alpha[4];
#pragma unroll
    for (int rr = 0; rr < 4; ++rr) {
      float mnew = fmaxf(mi[rr], rmax[rr]);
      alpha[rr] = exp2f(mi[rr] - mnew);
      mi[rr] = mnew;
    }
    float rsum[4] = {0.f, 0.f, 0.f, 0.f};
#pragma unroll
    for (int tj = 0; tj < 8; ++tj)
#pragma unroll
      for (int rr = 0; rr < 4; ++rr) {
        float p = exp2f(sc[tj][rr] - mi[rr]);
        sc[tj][rr] = p;
        rsum[rr] += p;
      }
#pragma unroll
    for (int d = 1; d < 16; d <<= 1)
#pragma unroll
      for (int rr = 0; rr < 4; ++rr) rsum[rr] += __shfl_xor(rsum[rr], d, 64);
#pragma unroll
    for (int rr = 0; rr < 4; ++rr) li[rr] = li[rr] * alpha[rr] + rsum[rr];
#pragma unroll
    for (int hj = 0; hj < 4; ++hj)
#pragma unroll
      for (int rr = 0; rr < 4; ++rr) o[hj][rr] *= alpha[rr];

    // ---- O += P @ V  (P: C-layout -> A-layout via per-wave LDS chunk) ----
    short* pw = &Ps[wave][0];
#pragma unroll
    for (int kc = 0; kc < 4; ++kc) {
#pragma unroll
      for (int tp = 0; tp < 2; ++tp) {
        int tj = kc * 2 + tp;
        int klc = tp * 16 + l15;
        int hi = (klc >> 3) * 16;
#pragma unroll
        for (int rr = 0; rr < 4; ++rr) {
          pw[(hi + quad * 4 + rr) * 8 + (klc & 7)] = f2bf(sc[tj][rr]);
        }
      }
      short8 ap = *(const short8*)(pw + (quad * 16 + l15) * 8);
#pragma unroll
      for (int hj = 0; hj < 4; ++hj) {
        short8 bv = *(const short8*)(Vs + ((kc * 4 + quad) * 64 + hj * 16 + l15) * 8);
        o[hj] = __builtin_amdgcn_mfma_f32_16x16x32_bf16(ap, bv, o[hj], 0, 0, 0);
      }
    }
  }

  // ---- epilogue: O / l -> Ob[B,T,D] bf16 ----
#pragma unroll
  for (int hj = 0; hj < 4; ++hj)
#pragma unroll
    for (int rr = 0; rr < 4; ++rr) {
      int q = qt * 128 + wave * 16 + quad * 4 + rr;
      Ob[((size_t)b * T_ + q) * D_ + h * 64 + hj * 16 + l15] = f2bf(o[hj][rr] / li[rr]);
    }
}

// ---------------- host launcher ----------------
extern "C" void kernel_launch(void* const* d_in, const int* in_sizes, int n_in,
                              void* d_out, int out_size, void* d_ws, size_t ws_size,
                              hipStream_t stream) {
  const float* x    = (const float*)d_in[0];
  const float* bias = (const float*)d_in[1];
  const float* Wqkv = (const float*)d_in[2];
  const float* bqkv = (const float*)d_in[3];
  const float* Wout = (const float*)d_in[4];
  const float* bout = (const float*)d_in[5];
  float* out = (float*)d_out;
  char* ws = (char*)d_ws;

  // workspace layout (~89 MB, lifetime-aliased)
  short* xb   = (short*)(ws + 0);          // x bf16 [8192][1024]   (dead after gemm1)
  short* Vt   = (short*)(ws + 0);          // V^T [BH][64][T]       (aliases xb)
  short* Wqt  = (short*)(ws + 16777216);   // Wqkv^T bf16 [3072][1024]
  short* Wot  = (short*)(ws + 23068672);   // Wout^T bf16 [1024][1024]
  short* Qb   = (short*)(ws + 25165824);   // Q [BH][T][64] (pre-scaled)
  short* Kb   = (short*)(ws + 41943040);   // K [BH][T][64]
  short* Vtmp = (short*)(ws + 58720256);   // V [BH][T][64]         (dead after btransV)
  short* Ob   = (short*)(ws + 58720256);   // attn out [B,T,D] bf16 (aliases Vtmp)
  short* PB   = (short*)(ws + 75497472);   // bias C-frag tiles bf16, 17.8 MB

  cast_x_kernel<<<8192, 256, 0, stream>>>(x, xb);
  tcast_kernel<<<dim3(96, 32), 256, 0, stream>>>(Wqkv, Wqt, 1024, 3072);
  tcast_kernel<<<dim3(32, 32), 256, 0, stream>>>(Wout, Wot, 1024, 1024);
  pb_kernel<<<544, 512, 0, stream>>>(bias, PB);
  gemm_qkv_kernel<<<dim3(24, 64), 256, 0, stream>>>(xb, Wqt, bqkv, Qb, Kb, Vtmp);
  btransV_kernel<<<dim3(64, 2, 64), 256, 0, stream>>>(Vtmp, Vt);
  attn_kernel<<<dim3(64, 16), 512, 0, stream>>>(Qb, Kb, Vt, PB, Ob);
  gemm_out_kernel<<<dim3(8, 64), 256, 0, stream>>>(Ob, Wot, bout, out);
}